// Round 8
// baseline (274.677 us; speedup 1.0000x reference)
//
#include <hip/hip_runtime.h>
#include <math.h>

#define FIN 128
#define FOUT 64
#define MAXDEG 64
#define BKT_SHIFT 9           // 512 dsts per bucket
#define BKT_CAP 10240         // mean 8163, +23 sigma

// ---------------- helpers ----------------

__device__ __forceinline__ float4 f4add(float4 a, float4 b) {
  return make_float4(a.x + b.x, a.y + b.y, a.z + b.z, a.w + b.w);
}
__device__ __forceinline__ float4 f4fma(float c, float4 v, float4 a) {
  return make_float4(fmaf(c, v.x, a.x), fmaf(c, v.y, a.y),
                     fmaf(c, v.z, a.z), fmaf(c, v.w, a.w));
}
__device__ __forceinline__ float4 f4shflxor(float4 v, int off) {
  return make_float4(__shfl_xor(v.x, off, 64), __shfl_xor(v.y, off, 64),
                     __shfl_xor(v.z, off, 64), __shfl_xor(v.w, off, 64));
}
__device__ __forceinline__ float red16(float v) {
  v += __shfl_xor(v, 1, 64);
  v += __shfl_xor(v, 2, 64);
  v += __shfl_xor(v, 4, 64);
  v += __shfl_xor(v, 8, 64);
  return v;
}
__device__ __forceinline__ float wave_sum(float v) {
#pragma unroll
  for (int off = 1; off <= 32; off <<= 1) v += __shfl_xor(v, off, 64);
  return v;
}

// logmap0 row factor: artanh(clip(n))/max(n,1e-15), c=1
__device__ __forceinline__ float row_scale(float ss) {
  float n  = sqrtf(ss);
  float nc = fmaxf(n, 1e-15f);
  float t  = fminf(nc, 1.0f - 1e-7f);
  float at = 0.5f * (log1pf(t) - log1pf(-t));
  return at / nc;
}

__device__ __forceinline__ float leaky(float v) {
  return (v >= 0.f) ? v : 0.01f * v;
}

// ---------------- kernel 0: zero bucket counters ----------------
__global__ __launch_bounds__(256) void k_pre(int* __restrict__ bcnt, int nb) {
  int t = blockIdx.x * 256 + threadIdx.x;
  if (t < nb) bcnt[t] = 0;
}

// ---------------- kernel 1: logmap0 + GEMM + leaky + fused projections ------
// LDS = xs only (32 KB -> 4 blocks/CU); W read straight from global (32 KB,
// L1-resident, 8 distinct float4 addrs/wave = broadcast). After the FMA loop
// the xs buffer is re-used (pad-65) to hold the u tile for the projection
// phase: wave w computes scl4[*].w = dot(u_row, wcol_w), replacing k_scal.
__global__ __launch_bounds__(256) void k_gemm(const float* __restrict__ x,
                                              const float* __restrict__ Wup,
                                              const float* __restrict__ Wpl,
                                              const float* __restrict__ Wlw,
                                              float* __restrict__ u,
                                              float* __restrict__ scl4, int N) {
  __shared__ float buf[64 * FIN];     // phase1: xs[k][n] = k*64+n; phase2: us[n][f] = n*65+f
  __shared__ float wls[4 * 64];       // projection weight columns
  __shared__ float ps[256];
  __shared__ float scl[64];

  int t = threadIdx.x;
  int n0 = blockIdx.x * 64;

  // ---- stage projection weights ----
  {
    int proj = t >> 6, f = t & 63;
    float wv = (proj == 0) ? Wpl[f * 2]
             : (proj == 1) ? Wpl[f * 2 + 1]
             : (proj == 2) ? Wlw[f] : Wlw[64 + f];
    wls[t] = wv;
  }
  // ---- stage x tile with transpose: x[n][k] -> xs[k][n] ----
  {
    int n  = t & 63;
    int kq = t >> 6;
    int gn = n0 + n;
    bool ok = gn < N;
    const float4* xr = (const float4*)(x + (size_t)gn * FIN);
#pragma unroll
    for (int m = 0; m < 8; ++m) {
      int kc = kq * 8 + m;
      float4 v = ok ? xr[kc] : make_float4(0.f, 0.f, 0.f, 0.f);
      buf[(kc * 4 + 0) * 64 + n] = v.x;
      buf[(kc * 4 + 1) * 64 + n] = v.y;
      buf[(kc * 4 + 2) * 64 + n] = v.z;
      buf[(kc * 4 + 3) * 64 + n] = v.w;
    }
  }
  __syncthreads();

  // ---- fused logmap0 norm ----
  {
    int n = t & 63, part = t >> 6;
    float s = 0.f;
#pragma unroll
    for (int k = part * 32; k < part * 32 + 32; ++k) {
      float v = buf[k * 64 + n];
      s = fmaf(v, v, s);
    }
    ps[t] = s;
  }
  __syncthreads();
  if (t < 64) {
    float ss = ps[t] + ps[t + 64] + ps[t + 128] + ps[t + 192];
    scl[t] = row_scale(ss);
  }
  __syncthreads();

  // ---- register-blocked FMA loop (W from global/L1) ----
  int wave = t >> 6, lane = t & 63;
  int wn = wave >> 1, wf = wave & 1;
  int i = lane & 7, j = lane >> 3;
  const float* xp = buf + wn * 32 + i * 4;
  const float* wg = Wup + wf * 32 + j * 4;
  float4 a0 = make_float4(0,0,0,0), a1 = a0, a2 = a0, a3 = a0;
#pragma unroll 8
  for (int k = 0; k < FIN; ++k) {
    float4 xv = *(const float4*)(xp + k * 64);
    float4 wv = *(const float4*)(wg + k * 64);
    a0 = f4fma(xv.x, wv, a0);
    a1 = f4fma(xv.y, wv, a1);
    a2 = f4fma(xv.z, wv, a2);
    a3 = f4fma(xv.w, wv, a3);
  }
  __syncthreads();   // all xs reads done; buf becomes us[n*65+f]

  // ---- epilogue: scale, leaky, store global + LDS tile ----
  int fbase = wf * 32 + j * 4;
#pragma unroll
  for (int r = 0; r < 4; ++r) {
    float4 acc = (r == 0) ? a0 : (r == 1) ? a1 : (r == 2) ? a2 : a3;
    int nl = wn * 32 + i * 4 + r;
    int gn = n0 + nl;
    float sc = scl[nl];
    float4 o = make_float4(leaky(sc * acc.x), leaky(sc * acc.y),
                           leaky(sc * acc.z), leaky(sc * acc.w));
    if (gn < N) *(float4*)(u + (size_t)gn * FOUT + fbase) = o;
    buf[nl * 65 + fbase]     = o.x;
    buf[nl * 65 + fbase + 1] = o.y;
    buf[nl * 65 + fbase + 2] = o.z;
    buf[nl * 65 + fbase + 3] = o.w;
  }
  __syncthreads();

  // ---- projection phase: wave w -> scl4 component w ----
  {
    int gn = n0 + lane;
    const float* ur = buf + lane * 65;       // banks (lane+f)%32 -> conflict-free
    const float* wc = wls + wave * 64;
    float acc = 0.f;
#pragma unroll 8
    for (int f = 0; f < 64; ++f) acc = fmaf(ur[f], wc[f], acc);
    if (gn < N) scl4[(size_t)gn * 4 + wave] = acc;
  }
}

// ---------------- kernel 2a: bin edges into dst-range buckets ----------------
__global__ __launch_bounds__(256) void k_binA(const int* __restrict__ ei, int E,
                                              int nb, int* __restrict__ bcnt,
                                              int2* __restrict__ stg) {
  __shared__ int hist[256];
  __shared__ int base[256];
  int t = threadIdx.x;
  hist[t] = 0;
  __syncthreads();

  int e0 = blockIdx.x * 4096 + t * 16;
  int sv[16], dv[16];
#pragma unroll
  for (int j = 0; j < 16; j += 4) {
    int e = e0 + j;
    if (e + 3 < E) {
      int4 s4 = *(const int4*)(ei + e);
      int4 d4 = *(const int4*)(ei + E + e);
      sv[j] = s4.x; sv[j+1] = s4.y; sv[j+2] = s4.z; sv[j+3] = s4.w;
      dv[j] = d4.x; dv[j+1] = d4.y; dv[j+2] = d4.z; dv[j+3] = d4.w;
    } else {
      for (int q = 0; q < 4; ++q) {
        int ee = e + q;
        sv[j+q] = (ee < E) ? ei[ee] : -1;
        dv[j+q] = (ee < E) ? ei[E + ee] : -1;
      }
    }
  }
#pragma unroll
  for (int j = 0; j < 16; ++j)
    if (dv[j] >= 0) atomicAdd(&hist[dv[j] >> BKT_SHIFT], 1);
  __syncthreads();
  if (t < nb) base[t] = atomicAdd(&bcnt[t], hist[t]);
  __syncthreads();
  hist[t] = 0;
  __syncthreads();
#pragma unroll
  for (int j = 0; j < 16; ++j) {
    if (dv[j] < 0) continue;
    int b = dv[j] >> BKT_SHIFT;
    int p = base[b] + atomicAdd(&hist[b], 1);
    if (p < BKT_CAP) stg[(size_t)b * BKT_CAP + p] = make_int2(sv[j], dv[j]);
  }
}

// ---------------- kernel 2b: per-bucket CSR placement, LDS cursors ----------
__global__ __launch_bounds__(256) void k_binB(const int2* __restrict__ stg,
                                              const int* __restrict__ bcnt,
                                              int N, int* __restrict__ deg,
                                              int* __restrict__ slots) {
  __shared__ int cur[512];
  int b = blockIdx.x, t = threadIdx.x;
  cur[t] = 0; cur[t + 256] = 0;
  __syncthreads();
  int cnt = min(bcnt[b], BKT_CAP);
  int dbase = b << BKT_SHIFT;
  const int2* sp = stg + (size_t)b * BKT_CAP;
  for (int i = t; i < cnt; i += 256) {
    int2 e = sp[i];
    int p = atomicAdd(&cur[e.y - dbase], 1);
    if (p < MAXDEG) slots[(size_t)e.y * MAXDEG + p] = e.x;
  }
  __syncthreads();
#pragma unroll
  for (int l = t; l < 512; l += 256) {
    int dst = dbase + l;
    if (dst < N) deg[dst] = min(cur[l], MAXDEG);
  }
}

// ---------------- kernel 3a: gate phase (scalar gather, 16 B/edge) ----------
__global__ __launch_bounds__(256) void k_aggA(const int* __restrict__ deg,
                                              const int* __restrict__ slots,
                                              const float4* __restrict__ scl4,
                                              float* __restrict__ selF,
                                              float* __restrict__ gq,
                                              float* __restrict__ tp, int N) {
  int wv = threadIdx.x >> 6, lane = threadIdx.x & 63;
  int i = blockIdx.x * 4 + wv;
  if (i >= N) return;
  int d = deg[i];
  int s = slots[(size_t)i * MAXDEG + lane];
  bool valid = lane < d;
  s = valid ? s : 0;
  float4 g = scl4[s];
  float sp0 = wave_sum(valid ? g.x : 0.f);
  float sp1 = wave_sum(valid ? g.y : 0.f);
  float sq2 = wave_sum(valid ? g.w : 0.f);
  float r0 = fmaxf(sp0, 0.f), r1 = fmaxf(sp1, 0.f);
  float m  = fmaxf(r0, r1);
  float e0 = expf(r0 - m), e1 = expf(r1 - m);
  float p  = e1 / (e0 + e1);
  float sel = (p > 0.48f) ? 1.f : 0.f;
  if (lane == 0) {
    float4 own = scl4[i];
    selF[i] = sel;
    gq[i]   = sel * own.z;   // selF[i] * q1[i]
    tp[i]   = sq2;           // sum_neigh . Wlw[64:]
  }
}

// ---------------- kernel 3b: weight phase (scalar gather, 4 B/edge) ---------
__global__ __launch_bounds__(256) void k_aggB(const int* __restrict__ deg,
                                              const int* __restrict__ slots,
                                              const float* __restrict__ gq,
                                              const float* __restrict__ tp,
                                              const float* __restrict__ selF,
                                              float* __restrict__ cF, int N) {
  int wv = threadIdx.x >> 6, lane = threadIdx.x & 63;
  int i = blockIdx.x * 4 + wv;
  if (i >= N) return;
  int d = deg[i];
  int s = slots[(size_t)i * MAXDEG + lane];
  bool valid = lane < d;
  s = valid ? s : 0;
  float v = gq[s];
  float t = tp[i] + wave_sum(valid ? v : 0.f);
  if (lane == 0)
    cF[i] = (selF[i] != 0.f) ? 1.f / (1.f + expf(-t)) : 0.f;
}

// ---------------- kernel 3c: vector phase (f32 gather, gated) ----------
__global__ __launch_bounds__(256) void k_agg3(const int* __restrict__ deg,
                                              const int* __restrict__ slots,
                                              const float* __restrict__ u,
                                              const float* __restrict__ cF,
                                              float* __restrict__ out, int N) {
  int wv = threadIdx.x >> 6, lane = threadIdx.x & 63;
  int i = blockIdx.x * 4 + wv;
  if (i >= N) return;
  int d = deg[i];
  const int* sl = slots + (size_t)i * MAXDEG;
  int sub = lane >> 4, l4 = lane & 15;
  float4 acc0 = make_float4(0, 0, 0, 0), acc1 = make_float4(0, 0, 0, 0);
  for (int e = 0; e < d; e += 16) {
    int4 sv = ((const int4*)(sl + e))[sub];
    int base = e + sub * 4;
    float c0 = 0.f, c1 = 0.f, c2 = 0.f, c3 = 0.f;
    if (base < d)     c0 = cF[sv.x];
    if (base + 1 < d) c1 = cF[sv.y];
    if (base + 2 < d) c2 = cF[sv.z];
    if (base + 3 < d) c3 = cF[sv.w];
    float4 v0 = make_float4(0,0,0,0), v1 = v0, v2 = v0, v3 = v0;
    if (c0 != 0.f) v0 = ((const float4*)(u + (size_t)sv.x * 64))[l4];
    if (c1 != 0.f) v1 = ((const float4*)(u + (size_t)sv.y * 64))[l4];
    if (c2 != 0.f) v2 = ((const float4*)(u + (size_t)sv.z * 64))[l4];
    if (c3 != 0.f) v3 = ((const float4*)(u + (size_t)sv.w * 64))[l4];
    acc0 = f4fma(c0, v0, acc0);
    acc0 = f4fma(c1, v1, acc0);
    acc1 = f4fma(c2, v2, acc1);
    acc1 = f4fma(c3, v3, acc1);
  }
  float4 acc = f4add(acc0, acc1);
  acc = f4add(acc, f4shflxor(acc, 16));
  acc = f4add(acc, f4shflxor(acc, 32));
  float4 uv = ((const float4*)(u + (size_t)i * 64))[l4];
  float4 ov = make_float4(uv.x + fmaxf(acc.x, 0.f), uv.y + fmaxf(acc.y, 0.f),
                          uv.z + fmaxf(acc.z, 0.f), uv.w + fmaxf(acc.w, 0.f));
  float ssp = ov.x * ov.x + ov.y * ov.y + ov.z * ov.z + ov.w * ov.w;
  float ss  = red16(ssp);
  float nc  = fmaxf(sqrtf(ss), 1e-15f);
  float th  = tanhf(nc);
  float fac = th / nc;
  float4 r = make_float4(ov.x * fac, ov.y * fac, ov.z * fac, ov.w * fac);
  float n2 = fmaxf(th, 1e-15f);
  float maxn = 1.0f - 4e-3f;
  float s = (n2 > maxn) ? (maxn / n2) : 1.0f;
  float4 res = make_float4(r.x * s, r.y * s, r.z * s, r.w * s);
  if (sub == 0) ((float4*)(out + (size_t)i * 64))[l4] = res;
}

// ---------------- launch ----------------
extern "C" void kernel_launch(void* const* d_in, const int* in_sizes, int n_in,
                              void* d_out, int out_size, void* d_ws, size_t ws_size,
                              hipStream_t stream) {
  const float* x   = (const float*)d_in[0];
  const int*   ei  = (const int*)d_in[1];
  const float* Wup = (const float*)d_in[2];
  const float* Wpl = (const float*)d_in[3];
  const float* Wlw = (const float*)d_in[4];
  float* out = (float*)d_out;

  int N = in_sizes[0] / FIN;     // 100000
  int E = in_sizes[1] / 2;       // 1600000
  int nb = (N + (1 << BKT_SHIFT) - 1) >> BKT_SHIFT;   // 196 buckets

  char* ws = (char*)d_ws;
  float* u     = (float*)ws;                            // 25.6 MB
  int*   slots = (int*)(u + (size_t)N * 64);            // 25.6 MB
  int2*  stg   = (int2*)(slots + (size_t)N * MAXDEG);   // 16.1 MB (binA->binB)
  size_t stg_sz = (size_t)nb * BKT_CAP * sizeof(int2);
  float* scl4  = (float*)((char*)stg + stg_sz);         // 1.6 MB (float4/node)
  int*   deg   = (int*)(scl4 + (size_t)N * 4);          // 0.4 MB
  float* selF  = (float*)(deg + N);                     // 0.4 MB
  float* gq    = selF + N;                              // 0.4 MB
  float* tp    = gq + N;                                // 0.4 MB
  float* cF    = tp + N;                                // 0.4 MB
  int*   bcnt  = (int*)(cF + N);                        // tiny

  k_pre<<<1, 256, 0, stream>>>(bcnt, nb);
  k_binA<<<(E + 4095) / 4096, 256, 0, stream>>>(ei, E, nb, bcnt, stg);
  k_binB<<<nb, 256, 0, stream>>>(stg, bcnt, N, deg, slots);
  k_gemm<<<(N + 63) / 64, 256, 0, stream>>>(x, Wup, Wpl, Wlw, u, scl4, N);
  int nblk = (N + 3) / 4;
  k_aggA<<<nblk, 256, 0, stream>>>(deg, slots, (const float4*)scl4, selF, gq, tp, N);
  k_aggB<<<nblk, 256, 0, stream>>>(deg, slots, gq, tp, selF, cF, N);
  k_agg3<<<nblk, 256, 0, stream>>>(deg, slots, u, cF, out, N);
}

// Round 9
// 258.908 us; speedup vs baseline: 1.0609x; 1.0609x over previous
//
#include <hip/hip_runtime.h>
#include <math.h>

#define FIN 128
#define FOUT 64
#define MAXDEG 64
#define BKT_SHIFT 9           // 512 dsts per bucket
#define BKT_CAP 10240         // mean 8163, +23 sigma

// ---------------- helpers ----------------

__device__ __forceinline__ float4 f4add(float4 a, float4 b) {
  return make_float4(a.x + b.x, a.y + b.y, a.z + b.z, a.w + b.w);
}
__device__ __forceinline__ float4 f4fma(float c, float4 v, float4 a) {
  return make_float4(fmaf(c, v.x, a.x), fmaf(c, v.y, a.y),
                     fmaf(c, v.z, a.z), fmaf(c, v.w, a.w));
}
__device__ __forceinline__ float4 f4shflxor(float4 v, int off) {
  return make_float4(__shfl_xor(v.x, off, 64), __shfl_xor(v.y, off, 64),
                     __shfl_xor(v.z, off, 64), __shfl_xor(v.w, off, 64));
}
__device__ __forceinline__ float red16(float v) {
  v += __shfl_xor(v, 1, 64);
  v += __shfl_xor(v, 2, 64);
  v += __shfl_xor(v, 4, 64);
  v += __shfl_xor(v, 8, 64);
  return v;
}
__device__ __forceinline__ float wave_sum(float v) {
#pragma unroll
  for (int off = 1; off <= 32; off <<= 1) v += __shfl_xor(v, off, 64);
  return v;
}

// logmap0 row factor: artanh(clip(n))/max(n,1e-15), c=1
__device__ __forceinline__ float row_scale(float ss) {
  float n  = sqrtf(ss);
  float nc = fmaxf(n, 1e-15f);
  float t  = fminf(nc, 1.0f - 1e-7f);
  float at = 0.5f * (log1pf(t) - log1pf(-t));
  return at / nc;
}

__device__ __forceinline__ float leaky(float v) {
  return (v >= 0.f) ? v : 0.01f * v;
}

// bf16 pack (RNE, returns 16-bit) / unpack uint2 -> 4 floats
__device__ __forceinline__ unsigned int bf16rne(float x) {
  unsigned int b = __float_as_uint(x);
  b += 0x7FFFu + ((b >> 16) & 1u);
  return b >> 16;
}
__device__ __forceinline__ float4 bf4(uint2 v) {
  return make_float4(__uint_as_float(v.x << 16),
                     __uint_as_float(v.x & 0xFFFF0000u),
                     __uint_as_float(v.y << 16),
                     __uint_as_float(v.y & 0xFFFF0000u));
}

// ---------------- kernel 1: [gemm tiles] U [binA chunks], block-partitioned --
// gemm: logmap0 + GEMM(128->64) + leaky + fused 4-way projections (scl4).
// binA: LDS-histogram counting sort of edges into 196 dst-range buckets.
// Independent work: binA's EA-bound writes hide in gemm's latency stalls.
__global__ __launch_bounds__(256) void k_main(const float* __restrict__ x,
                                              const float* __restrict__ Wup,
                                              const float* __restrict__ Wpl,
                                              const float* __restrict__ Wlw,
                                              float* __restrict__ u,
                                              float* __restrict__ scl4,
                                              const int* __restrict__ ei, int E,
                                              int nb, int* __restrict__ bcnt,
                                              int2* __restrict__ stg,
                                              int N, int gemmBlocks) {
  __shared__ float buf[64 * FIN];     // gemm ph1: xs[k][n]=k*64+n; ph2: us[n*65+f]
  __shared__ float wls[256];          // gemm: proj weights | binA: base[]
  __shared__ float ps[256];           // gemm: norm partials | binA: hist[]
  __shared__ float scl[64];

  int t = threadIdx.x;

  if (blockIdx.x >= gemmBlocks) {
    // ================= binA branch =================
    int* hist = (int*)ps;
    int* base = (int*)wls;
    int bb = blockIdx.x - gemmBlocks;
    hist[t] = 0;
    __syncthreads();
    int e0 = bb * 4096 + t * 16;
    int sv[16], dv[16];
#pragma unroll
    for (int j = 0; j < 16; j += 4) {
      int e = e0 + j;
      if (e + 3 < E) {
        int4 s4 = *(const int4*)(ei + e);
        int4 d4 = *(const int4*)(ei + E + e);
        sv[j] = s4.x; sv[j+1] = s4.y; sv[j+2] = s4.z; sv[j+3] = s4.w;
        dv[j] = d4.x; dv[j+1] = d4.y; dv[j+2] = d4.z; dv[j+3] = d4.w;
      } else {
        for (int q = 0; q < 4; ++q) {
          int ee = e + q;
          sv[j+q] = (ee < E) ? ei[ee] : -1;
          dv[j+q] = (ee < E) ? ei[E + ee] : -1;
        }
      }
    }
#pragma unroll
    for (int j = 0; j < 16; ++j)
      if (dv[j] >= 0) atomicAdd(&hist[dv[j] >> BKT_SHIFT], 1);
    __syncthreads();
    if (t < nb) base[t] = atomicAdd(&bcnt[t], hist[t]);
    __syncthreads();
    hist[t] = 0;
    __syncthreads();
#pragma unroll
    for (int j = 0; j < 16; ++j) {
      if (dv[j] < 0) continue;
      int b = dv[j] >> BKT_SHIFT;
      int p = base[b] + atomicAdd(&hist[b], 1);
      if (p < BKT_CAP) stg[(size_t)b * BKT_CAP + p] = make_int2(sv[j], dv[j]);
    }
    return;
  }

  // ================= gemm branch =================
  int n0 = blockIdx.x * 64;
  {
    int proj = t >> 6, f = t & 63;
    float wv = (proj == 0) ? Wpl[f * 2]
             : (proj == 1) ? Wpl[f * 2 + 1]
             : (proj == 2) ? Wlw[f] : Wlw[64 + f];
    wls[t] = wv;
  }
  {
    int n  = t & 63;
    int kq = t >> 6;
    int gn = n0 + n;
    bool ok = gn < N;
    const float4* xr = (const float4*)(x + (size_t)gn * FIN);
#pragma unroll
    for (int m = 0; m < 8; ++m) {
      int kc = kq * 8 + m;
      float4 v = ok ? xr[kc] : make_float4(0.f, 0.f, 0.f, 0.f);
      buf[(kc * 4 + 0) * 64 + n] = v.x;
      buf[(kc * 4 + 1) * 64 + n] = v.y;
      buf[(kc * 4 + 2) * 64 + n] = v.z;
      buf[(kc * 4 + 3) * 64 + n] = v.w;
    }
  }
  __syncthreads();

  {
    int n = t & 63, part = t >> 6;
    float s = 0.f;
#pragma unroll
    for (int k = part * 32; k < part * 32 + 32; ++k) {
      float v = buf[k * 64 + n];
      s = fmaf(v, v, s);
    }
    ps[t] = s;
  }
  __syncthreads();
  if (t < 64) {
    float ss = ps[t] + ps[t + 64] + ps[t + 128] + ps[t + 192];
    scl[t] = row_scale(ss);
  }
  __syncthreads();

  int wave = t >> 6, lane = t & 63;
  int wn = wave >> 1, wf = wave & 1;
  int i = lane & 7, j = lane >> 3;
  const float* xp = buf + wn * 32 + i * 4;
  const float* wg = Wup + wf * 32 + j * 4;
  float4 a0 = make_float4(0,0,0,0), a1 = a0, a2 = a0, a3 = a0;
#pragma unroll 8
  for (int k = 0; k < FIN; ++k) {
    float4 xv = *(const float4*)(xp + k * 64);
    float4 wv = *(const float4*)(wg + k * 64);
    a0 = f4fma(xv.x, wv, a0);
    a1 = f4fma(xv.y, wv, a1);
    a2 = f4fma(xv.z, wv, a2);
    a3 = f4fma(xv.w, wv, a3);
  }
  __syncthreads();   // xs dead; buf becomes us[n*65+f]

  int fbase = wf * 32 + j * 4;
#pragma unroll
  for (int r = 0; r < 4; ++r) {
    float4 acc = (r == 0) ? a0 : (r == 1) ? a1 : (r == 2) ? a2 : a3;
    int nl = wn * 32 + i * 4 + r;
    int gn = n0 + nl;
    float sc = scl[nl];
    float4 o = make_float4(leaky(sc * acc.x), leaky(sc * acc.y),
                           leaky(sc * acc.z), leaky(sc * acc.w));
    if (gn < N) *(float4*)(u + (size_t)gn * FOUT + fbase) = o;
    buf[nl * 65 + fbase]     = o.x;
    buf[nl * 65 + fbase + 1] = o.y;
    buf[nl * 65 + fbase + 2] = o.z;
    buf[nl * 65 + fbase + 3] = o.w;
  }
  __syncthreads();

  {
    int gn = n0 + lane;
    const float* ur = buf + lane * 65;       // (lane+f)%32 banks: conflict-free
    const float* wc = wls + wave * 64;
    float acc = 0.f;
#pragma unroll 8
    for (int f = 0; f < 64; ++f) acc = fmaf(ur[f], wc[f], acc);
    if (gn < N) scl4[(size_t)gn * 4 + wave] = acc;
  }
}

// ---------------- kernel 2: per-bucket CSR placement + sentinel padding -----
// Pads each slot row to a multiple of 16 with sentinel N, so agg3's gather
// loop needs no per-edge bounds checks (uw row N is zeroed by aggB).
__global__ __launch_bounds__(256) void k_binB(const int2* __restrict__ stg,
                                              const int* __restrict__ bcnt,
                                              int N, int* __restrict__ deg,
                                              int* __restrict__ slots) {
  __shared__ int cur[512];
  int b = blockIdx.x, t = threadIdx.x;
  cur[t] = 0; cur[t + 256] = 0;
  __syncthreads();
  int cnt = min(bcnt[b], BKT_CAP);
  int dbase = b << BKT_SHIFT;
  const int2* sp = stg + (size_t)b * BKT_CAP;
  for (int i = t; i < cnt; i += 256) {
    int2 e = sp[i];
    int p = atomicAdd(&cur[e.y - dbase], 1);
    if (p < MAXDEG) slots[(size_t)e.y * MAXDEG + p] = e.x;
  }
  __syncthreads();
#pragma unroll
  for (int l = t; l < 512; l += 256) {
    int dst = dbase + l;
    if (dst < N) {
      int c = min(cur[l], MAXDEG);
      deg[dst] = c;
      int cr = (c + 15) & ~15;
      for (int p = c; p < cr; ++p) slots[(size_t)dst * MAXDEG + p] = N;
    }
  }
}

// ---------------- kernel 3a: gate phase (scalar gather, 16 B/edge) ----------
__global__ __launch_bounds__(256) void k_aggA(const int* __restrict__ deg,
                                              const int* __restrict__ slots,
                                              const float4* __restrict__ scl4,
                                              float* __restrict__ selF,
                                              float* __restrict__ gq,
                                              float* __restrict__ tp, int N) {
  int wv = threadIdx.x >> 6, lane = threadIdx.x & 63;
  int i = blockIdx.x * 4 + wv;
  if (i >= N) return;
  int d = deg[i];
  int s = slots[(size_t)i * MAXDEG + lane];
  bool valid = lane < d;
  s = valid ? s : 0;
  float4 g = scl4[s];
  float sp0 = wave_sum(valid ? g.x : 0.f);
  float sp1 = wave_sum(valid ? g.y : 0.f);
  float sq2 = wave_sum(valid ? g.w : 0.f);
  float r0 = fmaxf(sp0, 0.f), r1 = fmaxf(sp1, 0.f);
  float m  = fmaxf(r0, r1);
  float e0 = expf(r0 - m), e1 = expf(r1 - m);
  float p  = e1 / (e0 + e1);
  float sel = (p > 0.48f) ? 1.f : 0.f;
  if (lane == 0) {
    float4 own = scl4[i];
    selF[i] = sel;
    gq[i]   = sel * own.z;   // selF[i] * q1[i]
    tp[i]   = sq2;           // sum_neigh . Wlw[64:]
  }
}

// ---------------- kernel 3b: weight phase + uw materialization --------------
// t = tp[i] + sum gq[s]; c = selF[i]*sigmoid(t); uw[i] = bf16(c * u[i]).
// All 64 lanes participate in the uw row (even lanes store packed pairs).
__global__ __launch_bounds__(256) void k_aggB(const int* __restrict__ deg,
                                              const int* __restrict__ slots,
                                              const float* __restrict__ gq,
                                              const float* __restrict__ tp,
                                              const float* __restrict__ selF,
                                              const float* __restrict__ u,
                                              unsigned int* __restrict__ uw,
                                              int N) {
  if (blockIdx.x == 0 && threadIdx.x < 32)      // zero sentinel row N
    uw[(size_t)N * 32 + threadIdx.x] = 0u;
  int wv = threadIdx.x >> 6, lane = threadIdx.x & 63;
  int i = blockIdx.x * 4 + wv;
  if (i >= N) return;
  int d = deg[i];
  int s = slots[(size_t)i * MAXDEG + lane];
  bool valid = lane < d;
  s = valid ? s : 0;
  float v = gq[s];
  float t = tp[i] + wave_sum(valid ? v : 0.f);
  float sig = 1.f / (1.f + expf(-t));
  float c = (selF[i] != 0.f) ? sig : 0.f;
  float val = c * u[(size_t)i * 64 + lane];
  unsigned int b = bf16rne(val);
  unsigned int partner = (unsigned int)__shfl_xor((int)b, 1, 64);
  if ((lane & 1) == 0)
    uw[(size_t)i * 32 + (lane >> 1)] = (b & 0xFFFFu) | (partner << 16);
}

// ---------------- kernel 3c: vector phase — ungated bf16 uw gather ----------
__global__ __launch_bounds__(256) void k_agg3(const int* __restrict__ deg,
                                              const int* __restrict__ slots,
                                              const float* __restrict__ u,
                                              const uint2* __restrict__ uw,
                                              float* __restrict__ out, int N) {
  int wv = threadIdx.x >> 6, lane = threadIdx.x & 63;
  int i = blockIdx.x * 4 + wv;
  if (i >= N) return;
  int d = deg[i];
  int dr = (d + 15) & ~15;            // slot rows sentinel-padded to x16
  const int* sl = slots + (size_t)i * MAXDEG;
  int sub = lane >> 4, l4 = lane & 15;
  float4 acc0 = make_float4(0, 0, 0, 0), acc1 = make_float4(0, 0, 0, 0);
  for (int e = 0; e < dr; e += 16) {
    int4 sv = ((const int4*)(sl + e))[sub];
    uint2 w0 = uw[(size_t)sv.x * 16 + l4];
    uint2 w1 = uw[(size_t)sv.y * 16 + l4];
    uint2 w2 = uw[(size_t)sv.z * 16 + l4];
    uint2 w3 = uw[(size_t)sv.w * 16 + l4];
    acc0 = f4add(acc0, f4add(bf4(w0), bf4(w1)));
    acc1 = f4add(acc1, f4add(bf4(w2), bf4(w3)));
  }
  float4 acc = f4add(acc0, acc1);
  acc = f4add(acc, f4shflxor(acc, 16));
  acc = f4add(acc, f4shflxor(acc, 32));
  float4 uv = ((const float4*)(u + (size_t)i * 64))[l4];
  float4 ov = make_float4(uv.x + fmaxf(acc.x, 0.f), uv.y + fmaxf(acc.y, 0.f),
                          uv.z + fmaxf(acc.z, 0.f), uv.w + fmaxf(acc.w, 0.f));
  float ssp = ov.x * ov.x + ov.y * ov.y + ov.z * ov.z + ov.w * ov.w;
  float ss  = red16(ssp);
  float nc  = fmaxf(sqrtf(ss), 1e-15f);
  float th  = tanhf(nc);
  float fac = th / nc;
  float4 r = make_float4(ov.x * fac, ov.y * fac, ov.z * fac, ov.w * fac);
  float n2 = fmaxf(th, 1e-15f);
  float maxn = 1.0f - 4e-3f;
  float s = (n2 > maxn) ? (maxn / n2) : 1.0f;
  float4 res = make_float4(r.x * s, r.y * s, r.z * s, r.w * s);
  if (sub == 0) ((float4*)(out + (size_t)i * 64))[l4] = res;
}

// ---------------- launch ----------------
extern "C" void kernel_launch(void* const* d_in, const int* in_sizes, int n_in,
                              void* d_out, int out_size, void* d_ws, size_t ws_size,
                              hipStream_t stream) {
  const float* x   = (const float*)d_in[0];
  const int*   ei  = (const int*)d_in[1];
  const float* Wup = (const float*)d_in[2];
  const float* Wpl = (const float*)d_in[3];
  const float* Wlw = (const float*)d_in[4];
  float* out = (float*)d_out;

  int N = in_sizes[0] / FIN;     // 100000
  int E = in_sizes[1] / 2;       // 1600000
  int nb = (N + (1 << BKT_SHIFT) - 1) >> BKT_SHIFT;   // 196 buckets

  char* ws = (char*)d_ws;
  float* u     = (float*)ws;                            // 25.6 MB
  int*   slots = (int*)(u + (size_t)N * 64);            // 25.6 MB
  char*  regB  = (char*)(slots + (size_t)N * MAXDEG);   // union: stg | uw
  size_t regB_sz = (size_t)nb * BKT_CAP * sizeof(int2); // 16.1 MB
  int2*  stg   = (int2*)regB;          // lifetime: k_main(binA) -> binB
  unsigned int* uwp = (unsigned int*)regB;  // lifetime: aggB -> agg3 ((N+1)*32 uints)
  float* scl4  = (float*)(regB + regB_sz);              // 1.6 MB
  int*   deg   = (int*)(scl4 + (size_t)N * 4);          // 0.4 MB
  float* selF  = (float*)(deg + N);                     // 0.4 MB
  float* gq    = selF + N;                              // 0.4 MB
  float* tp    = gq + N;                                // 0.4 MB
  int*   bcnt  = (int*)(tp + N);                        // tiny

  hipMemsetAsync(bcnt, 0, nb * sizeof(int), stream);

  int gemmBlocks = (N + 63) / 64;                 // 1563
  int binABlocks = (E + 4095) / 4096;             // 391
  k_main<<<gemmBlocks + binABlocks, 256, 0, stream>>>(
      x, Wup, Wpl, Wlw, u, scl4, ei, E, nb, bcnt, stg, N, gemmBlocks);
  k_binB<<<nb, 256, 0, stream>>>(stg, bcnt, N, deg, slots);
  int nblk = (N + 3) / 4;
  k_aggA<<<nblk, 256, 0, stream>>>(deg, slots, (const float4*)scl4, selF, gq, tp, N);
  k_aggB<<<nblk, 256, 0, stream>>>(deg, slots, gq, tp, selF, u, uwp, N);
  k_agg3<<<nblk, 256, 0, stream>>>(deg, slots, u, (const uint2*)uwp, out, N);
}

// Round 10
// 247.843 us; speedup vs baseline: 1.1083x; 1.0446x over previous
//
#include <hip/hip_runtime.h>
#include <math.h>

#define FIN 128
#define FOUT 64
#define MAXDEG 64
#define BKT_SHIFT 7           // 128 dsts per bucket
#define BKT_CAP 2560          // mean 2048, +11 sigma

// ---------------- helpers ----------------

__device__ __forceinline__ float4 f4add(float4 a, float4 b) {
  return make_float4(a.x + b.x, a.y + b.y, a.z + b.z, a.w + b.w);
}
__device__ __forceinline__ float4 f4fma(float c, float4 v, float4 a) {
  return make_float4(fmaf(c, v.x, a.x), fmaf(c, v.y, a.y),
                     fmaf(c, v.z, a.z), fmaf(c, v.w, a.w));
}
__device__ __forceinline__ float4 f4shflxor(float4 v, int off) {
  return make_float4(__shfl_xor(v.x, off, 64), __shfl_xor(v.y, off, 64),
                     __shfl_xor(v.z, off, 64), __shfl_xor(v.w, off, 64));
}
__device__ __forceinline__ float red16(float v) {
  v += __shfl_xor(v, 1, 64);
  v += __shfl_xor(v, 2, 64);
  v += __shfl_xor(v, 4, 64);
  v += __shfl_xor(v, 8, 64);
  return v;
}
__device__ __forceinline__ float wave_sum(float v) {
#pragma unroll
  for (int off = 1; off <= 32; off <<= 1) v += __shfl_xor(v, off, 64);
  return v;
}

// logmap0 row factor: artanh(clip(n))/max(n,1e-15), c=1
__device__ __forceinline__ float row_scale(float ss) {
  float n  = sqrtf(ss);
  float nc = fmaxf(n, 1e-15f);
  float t  = fminf(nc, 1.0f - 1e-7f);
  float at = 0.5f * (log1pf(t) - log1pf(-t));
  return at / nc;
}

__device__ __forceinline__ float leaky(float v) {
  return (v >= 0.f) ? v : 0.01f * v;
}

// bf16 pack (RNE) / unpack uint2 -> 4 floats
__device__ __forceinline__ unsigned int bf16rne(float x) {
  unsigned int b = __float_as_uint(x);
  b += 0x7FFFu + ((b >> 16) & 1u);
  return b >> 16;
}
__device__ __forceinline__ float4 bf4(uint2 v) {
  return make_float4(__uint_as_float(v.x << 16),
                     __uint_as_float(v.x & 0xFFFF0000u),
                     __uint_as_float(v.y << 16),
                     __uint_as_float(v.y & 0xFFFF0000u));
}

// ---------------- kernel 1: [gemm 128-node tiles] U [binA chunks] ------------
// gemm: logmap0 + GEMM(128->64) + leaky + fused projections. 8n x 4f lane
// tile, two 64-node xs tiles per block (2 LDS b128 per 32 FMA).
// binA: LDS-histogram counting sort of edges into 782 dst-range buckets.
__global__ __launch_bounds__(256) void k_main(const float* __restrict__ x,
                                              const float* __restrict__ Wup,
                                              const float* __restrict__ Wpl,
                                              const float* __restrict__ Wlw,
                                              float* __restrict__ u,
                                              float* __restrict__ scl4,
                                              const int* __restrict__ ei, int E,
                                              int nb, int* __restrict__ bcnt,
                                              int2* __restrict__ stg,
                                              int N, int gemmBlocks) {
  __shared__ float buf[2 * 64 * FIN];  // gemm: xs[tile][k][n] / us[n*66+f]; binA: hist+base
  __shared__ float wls[256];
  __shared__ float ps[256];
  __shared__ float scl[128];

  int t = threadIdx.x;

  if (blockIdx.x >= gemmBlocks) {
    // ================= binA branch =================
    int* hist = (int*)buf;
    int* base = hist + nb;
    int bb = blockIdx.x - gemmBlocks;
    for (int h = t; h < nb; h += 256) hist[h] = 0;
    __syncthreads();
    int e0 = bb * 4096 + t * 16;
    int sv[16], dv[16];
#pragma unroll
    for (int j = 0; j < 16; j += 4) {
      int e = e0 + j;
      if (e + 3 < E) {
        int4 s4 = *(const int4*)(ei + e);
        int4 d4 = *(const int4*)(ei + E + e);
        sv[j] = s4.x; sv[j+1] = s4.y; sv[j+2] = s4.z; sv[j+3] = s4.w;
        dv[j] = d4.x; dv[j+1] = d4.y; dv[j+2] = d4.z; dv[j+3] = d4.w;
      } else {
        for (int q = 0; q < 4; ++q) {
          int ee = e + q;
          sv[j+q] = (ee < E) ? ei[ee] : -1;
          dv[j+q] = (ee < E) ? ei[E + ee] : -1;
        }
      }
    }
#pragma unroll
    for (int j = 0; j < 16; ++j)
      if (dv[j] >= 0) atomicAdd(&hist[dv[j] >> BKT_SHIFT], 1);
    __syncthreads();
    for (int h = t; h < nb; h += 256)
      base[h] = hist[h] ? atomicAdd(&bcnt[h], hist[h]) : 0;
    __syncthreads();
    for (int h = t; h < nb; h += 256) hist[h] = 0;
    __syncthreads();
#pragma unroll
    for (int j = 0; j < 16; ++j) {
      if (dv[j] < 0) continue;
      int b = dv[j] >> BKT_SHIFT;
      int p = base[b] + atomicAdd(&hist[b], 1);
      if (p < BKT_CAP) stg[(size_t)b * BKT_CAP + p] = make_int2(sv[j], dv[j]);
    }
    return;
  }

  // ================= gemm branch: 128 nodes/block =================
  int n0 = blockIdx.x * 128;
  {
    int proj = t >> 6, f = t & 63;
    float wv = (proj == 0) ? Wpl[f * 2]
             : (proj == 1) ? Wpl[f * 2 + 1]
             : (proj == 2) ? Wlw[f] : Wlw[64 + f];
    wls[t] = wv;
  }
  // ---- stage x: thread handles half a row (16 float4) ----
  {
    int n    = t & 127;
    int khal = t >> 7;
    int gn = n0 + n;
    bool ok = gn < N;
    const float4* xr = (const float4*)(x + (size_t)gn * FIN);
    float* xb = buf + (n >> 6) * 8192;
    int nl = n & 63;
#pragma unroll
    for (int m = 0; m < 16; ++m) {
      int kc = khal * 16 + m;
      float4 v = ok ? xr[kc] : make_float4(0.f, 0.f, 0.f, 0.f);
      xb[(kc * 4 + 0) * 64 + nl] = v.x;
      xb[(kc * 4 + 1) * 64 + nl] = v.y;
      xb[(kc * 4 + 2) * 64 + nl] = v.z;
      xb[(kc * 4 + 3) * 64 + nl] = v.w;
    }
  }
  __syncthreads();

  // ---- fused logmap0 norm ----
  {
    int n = t & 127, part = t >> 7;
    const float* xb = buf + (n >> 6) * 8192;
    int nl = n & 63;
    float s = 0.f;
#pragma unroll
    for (int k = part * 64; k < part * 64 + 64; ++k) {
      float v = xb[k * 64 + nl];
      s = fmaf(v, v, s);
    }
    ps[t] = s;
  }
  __syncthreads();
  if (t < 128) scl[t] = row_scale(ps[t] + ps[t + 128]);
  __syncthreads();

  // ---- FMA loop: wave -> (tile, f-half); lane (i=l&7 -> 8 nodes, j=l>>3 -> 4f)
  int wave = t >> 6, lane = t & 63;
  int tile = wave >> 1, half = wave & 1;
  int i = lane & 7, j = lane >> 3;
  const float* xp = buf + tile * 8192 + i * 8;
  const float* wg = Wup + half * 32 + j * 4;
  float4 a0 = make_float4(0,0,0,0), a1 = a0, a2 = a0, a3 = a0;
  float4 a4 = a0, a5 = a0, a6 = a0, a7 = a0;
#pragma unroll 8
  for (int k = 0; k < FIN; ++k) {
    float4 xv0 = *(const float4*)(xp + k * 64);
    float4 xv1 = *(const float4*)(xp + k * 64 + 4);
    float4 wv = *(const float4*)(wg + k * 64);
    a0 = f4fma(xv0.x, wv, a0);
    a1 = f4fma(xv0.y, wv, a1);
    a2 = f4fma(xv0.z, wv, a2);
    a3 = f4fma(xv0.w, wv, a3);
    a4 = f4fma(xv1.x, wv, a4);
    a5 = f4fma(xv1.y, wv, a5);
    a6 = f4fma(xv1.z, wv, a6);
    a7 = f4fma(xv1.w, wv, a7);
  }
  __syncthreads();   // xs dead; buf becomes us[n*66+f]

  // ---- epilogue: scale, leaky, store global + LDS tile ----
  int fbase = half * 32 + j * 4;
#pragma unroll
  for (int r = 0; r < 8; ++r) {
    float4 acc = (r==0)?a0:(r==1)?a1:(r==2)?a2:(r==3)?a3:(r==4)?a4:(r==5)?a5:(r==6)?a6:a7;
    int nn = tile * 64 + i * 8 + r;
    int gn = n0 + nn;
    float sc = scl[nn];
    float4 o = make_float4(leaky(sc * acc.x), leaky(sc * acc.y),
                           leaky(sc * acc.z), leaky(sc * acc.w));
    if (gn < N) *(float4*)(u + (size_t)gn * FOUT + fbase) = o;
    buf[nn * 66 + fbase]     = o.x;
    buf[nn * 66 + fbase + 1] = o.y;
    buf[nn * 66 + fbase + 2] = o.z;
    buf[nn * 66 + fbase + 3] = o.w;
  }
  __syncthreads();

  // ---- projection phase: proj = t>>6, two nodes per thread ----
  {
    int proj = t >> 6;
    const float* wc = wls + proj * 64;
#pragma unroll
    for (int rep = 0; rep < 2; ++rep) {
      int n = (t & 63) + rep * 64;
      int gn = n0 + n;
      const float* ur = buf + n * 66;
      float acc = 0.f;
#pragma unroll 8
      for (int f = 0; f < 64; ++f) acc = fmaf(ur[f], wc[f], acc);
      if (gn < N) scl4[(size_t)gn * 4 + proj] = acc;
    }
  }
}

// ---------------- kernel 2: per-bucket CSR placement + sentinel padding -----
__global__ __launch_bounds__(256) void k_binB(const int2* __restrict__ stg,
                                              const int* __restrict__ bcnt,
                                              int N, int* __restrict__ deg,
                                              int* __restrict__ slots) {
  __shared__ int cur[128];
  int b = blockIdx.x, t = threadIdx.x;
  if (t < 128) cur[t] = 0;
  __syncthreads();
  int cnt = min(bcnt[b], BKT_CAP);
  int dbase = b << BKT_SHIFT;
  const int2* sp = stg + (size_t)b * BKT_CAP;
  for (int i = t; i < cnt; i += 256) {
    int2 e = sp[i];
    int p = atomicAdd(&cur[e.y - dbase], 1);
    if (p < MAXDEG) slots[(size_t)e.y * MAXDEG + p] = e.x;
  }
  __syncthreads();
  if (t < 128) {
    int dst = dbase + t;
    if (dst < N) {
      int c = min(cur[t], MAXDEG);
      deg[dst] = c;
      int cr = (c + 15) & ~15;
      for (int p = c; p < cr; ++p) slots[(size_t)dst * MAXDEG + p] = N;
    }
  }
}

// ---------------- kernel 3a: gate phase (scalar gather, 16 B/edge) ----------
__global__ __launch_bounds__(256) void k_aggA(const int* __restrict__ deg,
                                              const int* __restrict__ slots,
                                              const float4* __restrict__ scl4,
                                              float* __restrict__ selF,
                                              float* __restrict__ gq,
                                              float* __restrict__ tp, int N) {
  int wv = threadIdx.x >> 6, lane = threadIdx.x & 63;
  int i = blockIdx.x * 4 + wv;
  if (i >= N) return;
  int d = deg[i];
  int s = slots[(size_t)i * MAXDEG + lane];
  bool valid = lane < d;
  s = valid ? s : 0;
  float4 g = scl4[s];
  float sp0 = wave_sum(valid ? g.x : 0.f);
  float sp1 = wave_sum(valid ? g.y : 0.f);
  float sq2 = wave_sum(valid ? g.w : 0.f);
  float r0 = fmaxf(sp0, 0.f), r1 = fmaxf(sp1, 0.f);
  float m  = fmaxf(r0, r1);
  float e0 = expf(r0 - m), e1 = expf(r1 - m);
  float p  = e1 / (e0 + e1);
  float sel = (p > 0.48f) ? 1.f : 0.f;
  if (lane == 0) {
    float4 own = scl4[i];
    selF[i] = sel;
    gq[i]   = sel * own.z;   // selF[i] * q1[i]
    tp[i]   = sq2;           // sum_neigh . Wlw[64:]
  }
}

// ---------------- kernel 3b: weight phase + bf16 uw materialization ---------
__global__ __launch_bounds__(256) void k_aggB(const int* __restrict__ deg,
                                              const int* __restrict__ slots,
                                              const float* __restrict__ gq,
                                              const float* __restrict__ tp,
                                              const float* __restrict__ selF,
                                              const float* __restrict__ u,
                                              unsigned int* __restrict__ uw,
                                              int N) {
  if (blockIdx.x == 0 && threadIdx.x < 32)      // zero sentinel row N
    uw[(size_t)N * 32 + threadIdx.x] = 0u;
  int wv = threadIdx.x >> 6, lane = threadIdx.x & 63;
  int i = blockIdx.x * 4 + wv;
  if (i >= N) return;
  int d = deg[i];
  int s = slots[(size_t)i * MAXDEG + lane];
  bool valid = lane < d;
  s = valid ? s : 0;
  float v = gq[s];
  float t = tp[i] + wave_sum(valid ? v : 0.f);
  float sig = 1.f / (1.f + expf(-t));
  float c = (selF[i] != 0.f) ? sig : 0.f;
  float val = c * u[(size_t)i * 64 + lane];
  unsigned int b = bf16rne(val);
  unsigned int partner = (unsigned int)__shfl_xor((int)b, 1, 64);
  if ((lane & 1) == 0)
    uw[(size_t)i * 32 + (lane >> 1)] = (b & 0xFFFFu) | (partner << 16);
}

// ---------------- kernel 3c: vector phase — ungated bf16 uw gather ----------
__global__ __launch_bounds__(256) void k_agg3(const int* __restrict__ deg,
                                              const int* __restrict__ slots,
                                              const float* __restrict__ u,
                                              const uint2* __restrict__ uw,
                                              float* __restrict__ out, int N) {
  int wv = threadIdx.x >> 6, lane = threadIdx.x & 63;
  int i = blockIdx.x * 4 + wv;
  if (i >= N) return;
  int d = deg[i];
  int dr = (d + 15) & ~15;            // slot rows sentinel-padded to x16
  const int* sl = slots + (size_t)i * MAXDEG;
  int sub = lane >> 4, l4 = lane & 15;
  float4 acc0 = make_float4(0, 0, 0, 0), acc1 = make_float4(0, 0, 0, 0);
  for (int e = 0; e < dr; e += 16) {
    int4 sv = ((const int4*)(sl + e))[sub];
    uint2 w0 = uw[(size_t)sv.x * 16 + l4];
    uint2 w1 = uw[(size_t)sv.y * 16 + l4];
    uint2 w2 = uw[(size_t)sv.z * 16 + l4];
    uint2 w3 = uw[(size_t)sv.w * 16 + l4];
    acc0 = f4add(acc0, f4add(bf4(w0), bf4(w1)));
    acc1 = f4add(acc1, f4add(bf4(w2), bf4(w3)));
  }
  float4 acc = f4add(acc0, acc1);
  acc = f4add(acc, f4shflxor(acc, 16));
  acc = f4add(acc, f4shflxor(acc, 32));
  float4 uv = ((const float4*)(u + (size_t)i * 64))[l4];
  float4 ov = make_float4(uv.x + fmaxf(acc.x, 0.f), uv.y + fmaxf(acc.y, 0.f),
                          uv.z + fmaxf(acc.z, 0.f), uv.w + fmaxf(acc.w, 0.f));
  float ssp = ov.x * ov.x + ov.y * ov.y + ov.z * ov.z + ov.w * ov.w;
  float ss  = red16(ssp);
  float nc  = fmaxf(sqrtf(ss), 1e-15f);
  float th  = tanhf(nc);
  float fac = th / nc;
  float4 r = make_float4(ov.x * fac, ov.y * fac, ov.z * fac, ov.w * fac);
  float n2 = fmaxf(th, 1e-15f);
  float maxn = 1.0f - 4e-3f;
  float s = (n2 > maxn) ? (maxn / n2) : 1.0f;
  float4 res = make_float4(r.x * s, r.y * s, r.z * s, r.w * s);
  if (sub == 0) ((float4*)(out + (size_t)i * 64))[l4] = res;
}

// ---------------- launch ----------------
extern "C" void kernel_launch(void* const* d_in, const int* in_sizes, int n_in,
                              void* d_out, int out_size, void* d_ws, size_t ws_size,
                              hipStream_t stream) {
  const float* x   = (const float*)d_in[0];
  const int*   ei  = (const int*)d_in[1];
  const float* Wup = (const float*)d_in[2];
  const float* Wpl = (const float*)d_in[3];
  const float* Wlw = (const float*)d_in[4];
  float* out = (float*)d_out;

  int N = in_sizes[0] / FIN;     // 100000
  int E = in_sizes[1] / 2;       // 1600000
  int nb = (N + (1 << BKT_SHIFT) - 1) >> BKT_SHIFT;   // 782 buckets

  char* ws = (char*)d_ws;
  float* u     = (float*)ws;                            // 25.6 MB
  int*   slots = (int*)(u + (size_t)N * 64);            // 25.6 MB
  char*  regB  = (char*)(slots + (size_t)N * MAXDEG);   // union: stg | uw
  size_t regB_sz = (size_t)nb * BKT_CAP * sizeof(int2); // 16.0 MB
  int2*  stg   = (int2*)regB;               // lifetime: k_main(binA) -> binB
  unsigned int* uwp = (unsigned int*)regB;  // lifetime: aggB -> agg3
  float* scl4  = (float*)(regB + regB_sz);              // 1.6 MB
  int*   deg   = (int*)(scl4 + (size_t)N * 4);          // 0.4 MB
  float* selF  = (float*)(deg + N);                     // 0.4 MB
  float* gq    = selF + N;                              // 0.4 MB
  float* tp    = gq + N;                                // 0.4 MB
  int*   bcnt  = (int*)(tp + N);                        // tiny

  hipMemsetAsync(bcnt, 0, nb * sizeof(int), stream);

  int gemmBlocks = (N + 127) / 128;               // 782
  int binABlocks = (E + 4095) / 4096;             // 391
  k_main<<<gemmBlocks + binABlocks, 256, 0, stream>>>(
      x, Wup, Wpl, Wlw, u, scl4, ei, E, nb, bcnt, stg, N, gemmBlocks);
  k_binB<<<nb, 256, 0, stream>>>(stg, bcnt, N, deg, slots);
  int nblk = (N + 3) / 4;
  k_aggA<<<nblk, 256, 0, stream>>>(deg, slots, (const float4*)scl4, selF, gq, tp, N);
  k_aggB<<<nblk, 256, 0, stream>>>(deg, slots, gq, tp, selF, u, uwp, N);
  k_agg3<<<nblk, 256, 0, stream>>>(deg, slots, u, (const uint2*)uwp, out, N);
}

// Round 11
// 244.404 us; speedup vs baseline: 1.1239x; 1.0141x over previous
//
#include <hip/hip_runtime.h>
#include <math.h>

#define FIN 128
#define FOUT 64
#define MAXDEG 64
#define BKT_SHIFT 7           // 128 dsts per bucket
#define BKT_CAP 2560          // mean 2048, +11 sigma

// ---------------- helpers ----------------

__device__ __forceinline__ float4 f4add(float4 a, float4 b) {
  return make_float4(a.x + b.x, a.y + b.y, a.z + b.z, a.w + b.w);
}
__device__ __forceinline__ float4 f4fma(float c, float4 v, float4 a) {
  return make_float4(fmaf(c, v.x, a.x), fmaf(c, v.y, a.y),
                     fmaf(c, v.z, a.z), fmaf(c, v.w, a.w));
}
__device__ __forceinline__ float4 f4shflxor(float4 v, int off) {
  return make_float4(__shfl_xor(v.x, off, 64), __shfl_xor(v.y, off, 64),
                     __shfl_xor(v.z, off, 64), __shfl_xor(v.w, off, 64));
}
__device__ __forceinline__ float red16(float v) {
  v += __shfl_xor(v, 1, 64);
  v += __shfl_xor(v, 2, 64);
  v += __shfl_xor(v, 4, 64);
  v += __shfl_xor(v, 8, 64);
  return v;
}
__device__ __forceinline__ float wave_sum(float v) {
#pragma unroll
  for (int off = 1; off <= 32; off <<= 1) v += __shfl_xor(v, off, 64);
  return v;
}

// logmap0 row factor: artanh(clip(n))/max(n,1e-15), c=1
__device__ __forceinline__ float row_scale(float ss) {
  float n  = sqrtf(ss);
  float nc = fmaxf(n, 1e-15f);
  float t  = fminf(nc, 1.0f - 1e-7f);
  float at = 0.5f * (log1pf(t) - log1pf(-t));
  return at / nc;
}

__device__ __forceinline__ float leaky(float v) {
  return (v >= 0.f) ? v : 0.01f * v;
}

// bf16 pack (RNE) / unpack uint2 -> 4 floats
__device__ __forceinline__ unsigned int bf16rne(float x) {
  unsigned int b = __float_as_uint(x);
  b += 0x7FFFu + ((b >> 16) & 1u);
  return b >> 16;
}
__device__ __forceinline__ float4 bf4(uint2 v) {
  return make_float4(__uint_as_float(v.x << 16),
                     __uint_as_float(v.x & 0xFFFF0000u),
                     __uint_as_float(v.y << 16),
                     __uint_as_float(v.y & 0xFFFF0000u));
}

// ---------------- kernel 1: [gemm 128-node tiles] U [binA chunks] ------------
__global__ __launch_bounds__(256) void k_main(const float* __restrict__ x,
                                              const float* __restrict__ Wup,
                                              const float* __restrict__ Wpl,
                                              const float* __restrict__ Wlw,
                                              float* __restrict__ u,
                                              float* __restrict__ scl4,
                                              const int* __restrict__ ei, int E,
                                              int nb, int* __restrict__ bcnt,
                                              int2* __restrict__ stg,
                                              int N, int gemmBlocks) {
  __shared__ float buf[2 * 64 * FIN];  // gemm: xs[tile][k][n] / us[n*67+f]; binA: hist+base
  __shared__ float wls[256];
  __shared__ float ps[256];
  __shared__ float scl[128];

  int t = threadIdx.x;

  if (blockIdx.x >= gemmBlocks) {
    // ================= binA branch =================
    int* hist = (int*)buf;
    int* base = hist + nb;
    int bb = blockIdx.x - gemmBlocks;
    for (int h = t; h < nb; h += 256) hist[h] = 0;
    __syncthreads();
    int e0 = bb * 4096 + t * 16;
    int sv[16], dv[16];
#pragma unroll
    for (int j = 0; j < 16; j += 4) {
      int e = e0 + j;
      if (e + 3 < E) {
        int4 s4 = *(const int4*)(ei + e);
        int4 d4 = *(const int4*)(ei + E + e);
        sv[j] = s4.x; sv[j+1] = s4.y; sv[j+2] = s4.z; sv[j+3] = s4.w;
        dv[j] = d4.x; dv[j+1] = d4.y; dv[j+2] = d4.z; dv[j+3] = d4.w;
      } else {
        for (int q = 0; q < 4; ++q) {
          int ee = e + q;
          sv[j+q] = (ee < E) ? ei[ee] : -1;
          dv[j+q] = (ee < E) ? ei[E + ee] : -1;
        }
      }
    }
#pragma unroll
    for (int j = 0; j < 16; ++j)
      if (dv[j] >= 0) atomicAdd(&hist[dv[j] >> BKT_SHIFT], 1);
    __syncthreads();
    for (int h = t; h < nb; h += 256)
      base[h] = hist[h] ? atomicAdd(&bcnt[h], hist[h]) : 0;
    __syncthreads();
    for (int h = t; h < nb; h += 256) hist[h] = 0;
    __syncthreads();
#pragma unroll
    for (int j = 0; j < 16; ++j) {
      if (dv[j] < 0) continue;
      int b = dv[j] >> BKT_SHIFT;
      int p = base[b] + atomicAdd(&hist[b], 1);
      if (p < BKT_CAP) stg[(size_t)b * BKT_CAP + p] = make_int2(sv[j], dv[j]);
    }
    return;
  }

  // ================= gemm branch: 128 nodes/block =================
  int n0 = blockIdx.x * 128;
  {
    int proj = t >> 6, f = t & 63;
    float wv = (proj == 0) ? Wpl[f * 2]
             : (proj == 1) ? Wpl[f * 2 + 1]
             : (proj == 2) ? Wlw[f] : Wlw[64 + f];
    wls[t] = wv;
  }
  {
    int n    = t & 127;
    int khal = t >> 7;
    int gn = n0 + n;
    bool ok = gn < N;
    const float4* xr = (const float4*)(x + (size_t)gn * FIN);
    float* xb = buf + (n >> 6) * 8192;
    int nl = n & 63;
#pragma unroll
    for (int m = 0; m < 16; ++m) {
      int kc = khal * 16 + m;
      float4 v = ok ? xr[kc] : make_float4(0.f, 0.f, 0.f, 0.f);
      xb[(kc * 4 + 0) * 64 + nl] = v.x;
      xb[(kc * 4 + 1) * 64 + nl] = v.y;
      xb[(kc * 4 + 2) * 64 + nl] = v.z;
      xb[(kc * 4 + 3) * 64 + nl] = v.w;
    }
  }
  __syncthreads();

  {
    int n = t & 127, part = t >> 7;
    const float* xb = buf + (n >> 6) * 8192;
    int nl = n & 63;
    float s = 0.f;
#pragma unroll
    for (int k = part * 64; k < part * 64 + 64; ++k) {
      float v = xb[k * 64 + nl];
      s = fmaf(v, v, s);
    }
    ps[t] = s;
  }
  __syncthreads();
  if (t < 128) scl[t] = row_scale(ps[t] + ps[t + 128]);
  __syncthreads();

  int wave = t >> 6, lane = t & 63;
  int tile = wave >> 1, half = wave & 1;
  int i = lane & 7, j = lane >> 3;
  const float* xp = buf + tile * 8192 + i * 8;
  const float* wg = Wup + half * 32 + j * 4;
  float4 a0 = make_float4(0,0,0,0), a1 = a0, a2 = a0, a3 = a0;
  float4 a4 = a0, a5 = a0, a6 = a0, a7 = a0;
#pragma unroll 8
  for (int k = 0; k < FIN; ++k) {
    float4 xv0 = *(const float4*)(xp + k * 64);
    float4 xv1 = *(const float4*)(xp + k * 64 + 4);
    float4 wv = *(const float4*)(wg + k * 64);
    a0 = f4fma(xv0.x, wv, a0);
    a1 = f4fma(xv0.y, wv, a1);
    a2 = f4fma(xv0.z, wv, a2);
    a3 = f4fma(xv0.w, wv, a3);
    a4 = f4fma(xv1.x, wv, a4);
    a5 = f4fma(xv1.y, wv, a5);
    a6 = f4fma(xv1.z, wv, a6);
    a7 = f4fma(xv1.w, wv, a7);
  }
  __syncthreads();   // xs dead; buf becomes us[n*67+f]

  int fbase = half * 32 + j * 4;
#pragma unroll
  for (int r = 0; r < 8; ++r) {
    float4 acc = (r==0)?a0:(r==1)?a1:(r==2)?a2:(r==3)?a3:(r==4)?a4:(r==5)?a5:(r==6)?a6:a7;
    int nn = tile * 64 + i * 8 + r;
    int gn = n0 + nn;
    float sc = scl[nn];
    float4 o = make_float4(leaky(sc * acc.x), leaky(sc * acc.y),
                           leaky(sc * acc.z), leaky(sc * acc.w));
    if (gn < N) *(float4*)(u + (size_t)gn * FOUT + fbase) = o;
    buf[nn * 67 + fbase]     = o.x;    // stride 67: 536%32=24 -> 2-way (free)
    buf[nn * 67 + fbase + 1] = o.y;
    buf[nn * 67 + fbase + 2] = o.z;
    buf[nn * 67 + fbase + 3] = o.w;
  }
  __syncthreads();

  {
    int proj = t >> 6;
    const float* wc = wls + proj * 64;
#pragma unroll
    for (int rep = 0; rep < 2; ++rep) {
      int n = (t & 63) + rep * 64;
      int gn = n0 + n;
      const float* ur = buf + n * 67;   // (3n+f)%32: conflict-free across lanes
      float acc = 0.f;
#pragma unroll 8
      for (int f = 0; f < 64; ++f) acc = fmaf(ur[f], wc[f], acc);
      if (gn < N) scl4[(size_t)gn * 4 + proj] = acc;
    }
  }
}

// ---------------- kernel 2: per-bucket CSR placement + sentinel padding -----
__global__ __launch_bounds__(256) void k_binB(const int2* __restrict__ stg,
                                              const int* __restrict__ bcnt,
                                              int N, int* __restrict__ deg,
                                              int* __restrict__ slots) {
  __shared__ int cur[128];
  int b = blockIdx.x, t = threadIdx.x;
  if (t < 128) cur[t] = 0;
  __syncthreads();
  int cnt = min(bcnt[b], BKT_CAP);
  int dbase = b << BKT_SHIFT;
  const int2* sp = stg + (size_t)b * BKT_CAP;
  for (int i = t; i < cnt; i += 256) {
    int2 e = sp[i];
    int p = atomicAdd(&cur[e.y - dbase], 1);
    if (p < MAXDEG) slots[(size_t)e.y * MAXDEG + p] = e.x;
  }
  __syncthreads();
  if (t < 128) {
    int dst = dbase + t;
    if (dst < N) {
      int c = min(cur[t], MAXDEG);
      deg[dst] = c;
      int cr = (c + 15) & ~15;
      for (int p = c; p < cr; ++p) slots[(size_t)dst * MAXDEG + p] = N;
    }
  }
}

// ---------------- kernel 3a: gate phase (scalar gather, 16 B/edge) ----------
__global__ __launch_bounds__(256) void k_aggA(const int* __restrict__ deg,
                                              const int* __restrict__ slots,
                                              const float4* __restrict__ scl4,
                                              float* __restrict__ selF,
                                              float* __restrict__ gq,
                                              float* __restrict__ tp, int N) {
  int wv = threadIdx.x >> 6, lane = threadIdx.x & 63;
  int i = blockIdx.x * 4 + wv;
  if (i >= N) return;
  int d = deg[i];
  int s = slots[(size_t)i * MAXDEG + lane];
  bool valid = lane < d;
  s = valid ? s : 0;
  float4 g = scl4[s];
  float sp0 = wave_sum(valid ? g.x : 0.f);
  float sp1 = wave_sum(valid ? g.y : 0.f);
  float sq2 = wave_sum(valid ? g.w : 0.f);
  float r0 = fmaxf(sp0, 0.f), r1 = fmaxf(sp1, 0.f);
  float m  = fmaxf(r0, r1);
  float e0 = expf(r0 - m), e1 = expf(r1 - m);
  float p  = e1 / (e0 + e1);
  float sel = (p > 0.48f) ? 1.f : 0.f;
  if (lane == 0) {
    float4 own = scl4[i];
    selF[i] = sel;
    gq[i]   = sel * own.z;   // selF[i] * q1[i]
    tp[i]   = sq2;           // sum_neigh . Wlw[64:]
  }
}

// ---------------- kernel 3b: weight phase + bf16 uw materialization ---------
// u-read skipped (wave-uniform) for unselected nodes: uw row is zero anyway.
__global__ __launch_bounds__(256) void k_aggB(const int* __restrict__ deg,
                                              const int* __restrict__ slots,
                                              const float* __restrict__ gq,
                                              const float* __restrict__ tp,
                                              const float* __restrict__ selF,
                                              const float* __restrict__ u,
                                              unsigned int* __restrict__ uw,
                                              int N) {
  if (blockIdx.x == 0 && threadIdx.x < 32)      // zero sentinel row N
    uw[(size_t)N * 32 + threadIdx.x] = 0u;
  int wv = threadIdx.x >> 6, lane = threadIdx.x & 63;
  int i = blockIdx.x * 4 + wv;
  if (i >= N) return;
  int d = deg[i];
  int s = slots[(size_t)i * MAXDEG + lane];
  bool valid = lane < d;
  s = valid ? s : 0;
  float v = gq[s];
  float t = tp[i] + wave_sum(valid ? v : 0.f);
  float seli = selF[i];
  float val = 0.f;
  if (seli != 0.f) {                   // wave-uniform branch
    float sig = 1.f / (1.f + expf(-t));
    val = sig * u[(size_t)i * 64 + lane];
  }
  unsigned int b = bf16rne(val);
  unsigned int partner = (unsigned int)__shfl_xor((int)b, 1, 64);
  if ((lane & 1) == 0)
    uw[(size_t)i * 32 + (lane >> 1)] = (b & 0xFFFFu) | (partner << 16);
}

// ---------------- kernel 3c: vector phase — ballot-compacted uw gather ------
// Lane-per-edge flag load (selF, 4 B, L2) -> __ballot -> LDS-compacted list of
// selected srcs (sentinel N rows are zero) -> ungated 8-rows/iter bf16 gather.
// Skips ~half the 128 B row gathers exactly (unselected rows are zero).
__global__ __launch_bounds__(256) void k_agg3(const int* __restrict__ deg,
                                              const int* __restrict__ slots,
                                              const float* __restrict__ selF,
                                              const float* __restrict__ u,
                                              const uint2* __restrict__ uw,
                                              float* __restrict__ out, int N) {
  __shared__ int comp[4][64];
  int wv = threadIdx.x >> 6, lane = threadIdx.x & 63;
  int i = blockIdx.x * 4 + wv;
  if (i >= N) return;
  int d = deg[i];
  bool valid = lane < d;
  int s = valid ? slots[(size_t)i * MAXDEG + lane] : 0;
  bool flag = valid && (selF[s] != 0.f);
  unsigned long long mask = __ballot(flag);
  int cnt = __popcll(mask);
  comp[wv][lane] = N;                  // sentinel: uw row N is zeroed
  int rank = __popcll(mask & ((1ull << lane) - 1ull));
  if (flag) comp[wv][rank] = s;
  int sub = lane >> 4, l4 = lane & 15;
  float4 acc0 = make_float4(0, 0, 0, 0), acc1 = acc0;
  for (int k0 = 0; k0 < cnt; k0 += 8) {
    int s0 = comp[wv][k0 + sub];
    int s1 = comp[wv][k0 + sub + 4];
    uint2 w0 = uw[(size_t)s0 * 16 + l4];
    uint2 w1 = uw[(size_t)s1 * 16 + l4];
    acc0 = f4add(acc0, bf4(w0));
    acc1 = f4add(acc1, bf4(w1));
  }
  float4 acc = f4add(acc0, acc1);
  acc = f4add(acc, f4shflxor(acc, 16));
  acc = f4add(acc, f4shflxor(acc, 32));
  float4 uv = ((const float4*)(u + (size_t)i * 64))[l4];
  float4 ov = make_float4(uv.x + fmaxf(acc.x, 0.f), uv.y + fmaxf(acc.y, 0.f),
                          uv.z + fmaxf(acc.z, 0.f), uv.w + fmaxf(acc.w, 0.f));
  float ssp = ov.x * ov.x + ov.y * ov.y + ov.z * ov.z + ov.w * ov.w;
  float ss  = red16(ssp);
  float nc  = fmaxf(sqrtf(ss), 1e-15f);
  float th  = tanhf(nc);
  float fac = th / nc;
  float4 r = make_float4(ov.x * fac, ov.y * fac, ov.z * fac, ov.w * fac);
  float n2 = fmaxf(th, 1e-15f);
  float maxn = 1.0f - 4e-3f;
  float sc = (n2 > maxn) ? (maxn / n2) : 1.0f;
  float4 res = make_float4(r.x * sc, r.y * sc, r.z * sc, r.w * sc);
  if (sub == 0) ((float4*)(out + (size_t)i * 64))[l4] = res;
}

// ---------------- launch ----------------
extern "C" void kernel_launch(void* const* d_in, const int* in_sizes, int n_in,
                              void* d_out, int out_size, void* d_ws, size_t ws_size,
                              hipStream_t stream) {
  const float* x   = (const float*)d_in[0];
  const int*   ei  = (const int*)d_in[1];
  const float* Wup = (const float*)d_in[2];
  const float* Wpl = (const float*)d_in[3];
  const float* Wlw = (const float*)d_in[4];
  float* out = (float*)d_out;

  int N = in_sizes[0] / FIN;     // 100000
  int E = in_sizes[1] / 2;       // 1600000
  int nb = (N + (1 << BKT_SHIFT) - 1) >> BKT_SHIFT;   // 782 buckets

  char* ws = (char*)d_ws;
  float* u     = (float*)ws;                            // 25.6 MB
  int*   slots = (int*)(u + (size_t)N * 64);            // 25.6 MB
  char*  regB  = (char*)(slots + (size_t)N * MAXDEG);   // union: stg | uw
  size_t regB_sz = (size_t)nb * BKT_CAP * sizeof(int2); // 16.0 MB
  int2*  stg   = (int2*)regB;               // lifetime: k_main(binA) -> binB
  unsigned int* uwp = (unsigned int*)regB;  // lifetime: aggB -> agg3
  float* scl4  = (float*)(regB + regB_sz);              // 1.6 MB
  int*   deg   = (int*)(scl4 + (size_t)N * 4);          // 0.4 MB
  float* selF  = (float*)(deg + N);                     // 0.4 MB
  float* gq    = selF + N;                              // 0.4 MB
  float* tp    = gq + N;                                // 0.4 MB
  int*   bcnt  = (int*)(tp + N);                        // tiny

  hipMemsetAsync(bcnt, 0, nb * sizeof(int), stream);

  int gemmBlocks = (N + 127) / 128;               // 782
  int binABlocks = (E + 4095) / 4096;             // 391
  k_main<<<gemmBlocks + binABlocks, 256, 0, stream>>>(
      x, Wup, Wpl, Wlw, u, scl4, ei, E, nb, bcnt, stg, N, gemmBlocks);
  k_binB<<<nb, 256, 0, stream>>>(stg, bcnt, N, deg, slots);
  int nblk = (N + 3) / 4;
  k_aggA<<<nblk, 256, 0, stream>>>(deg, slots, (const float4*)scl4, selF, gq, tp, N);
  k_aggB<<<nblk, 256, 0, stream>>>(deg, slots, gq, tp, selF, u, uwp, N);
  k_agg3<<<nblk, 256, 0, stream>>>(deg, slots, selF, u, (const uint2*)uwp, out, N);
}